// Round 2
// baseline (592.666 us; speedup 1.0000x reference)
//
#include <hip/hip_runtime.h>
#include <math.h>

#define Hh 24
#define Ww 24
#define Nn 576
#define Dd 1024
#define Bb 32
#define Kk 256
#define Mm 128
#define TOKSTRIDE (577 * 1024)

// Per-batch scratch lives INSIDE d_out: batch b owns out[b*Mm*Dd .. (b+1)*Mm*Dd).
// Scratch occupies the first ~5825 elements (rows 0..5) of the batch region and
// is consumed (via LDS) before those rows are overwritten. d_ws is NOT used.
// Element offsets within a batch region:
#define R0_OFF 0      // roots0           : 576 int
#define CNTS_OFF 576  // counts           : 576 int
#define MEMB_OFF 1152 // members (sorted) : 576 int
#define OFFS_OFF 1728 // offsets per root : 576 int
#define ORD_OFF 2304  // ord_idx (top-256): 256 int
#define CNT_OFF 2560  // cnt_sel          : 256 int
#define OUTI_OFF 2816 // out_idx (top-128): 128 int
#define P_OFF 2944    // p = patch.u      : 576 float
#define SC_OFF 3520   // scores           : 256 float
#define QC_OFF 3776   // qcls             : 1024 float
#define U_OFF 4800    // u = qcls.v_w     : 1024 float
#define T_OFF 5824    // t = qcls.v_b     : 1 float
// total 5825 < 6*1024, batch region = 128*1024 elements.

__device__ __forceinline__ float* batch_base(float* out, int b) {
  return out + (size_t)b * Mm * Dd;
}

// ---------------------------------------------------------------------------
// K1: depthwise 3x3 conv (SAME, zero pad) + pointwise 9xD + softmax over 9
//     + duplicate-accumulated clipped-neighbor affinity row + argmax
//     (tie -> lowest col) => roots0[b,n]. One block per (b,n), 256 thr over D.
// ---------------------------------------------------------------------------
__global__ __launch_bounds__(256) void affinity_root_kernel(
    const float* __restrict__ tok2d, const float* __restrict__ dw_w,
    const float* __restrict__ pw_w, const float* __restrict__ pw_b,
    float* __restrict__ outb) {
  int blk = blockIdx.x;
  int b = blk / Nn, n = blk % Nn;
  int y = n / Ww, x = n % Ww;
  int tid = threadIdx.x;
  const float* patch = tok2d + (size_t)b * TOKSTRIDE + Dd;  // skip cls token

  float acc[9];
#pragma unroll
  for (int o = 0; o < 9; o++) acc[o] = 0.f;

  for (int d = tid; d < Dd; d += 256) {
    float c = 0.f;
#pragma unroll
    for (int ky = 0; ky < 3; ky++) {
      int yy = y + ky - 1;
      if (yy < 0 || yy >= Hh) continue;  // wave-uniform (n fixed per block)
#pragma unroll
      for (int kx = 0; kx < 3; kx++) {
        int xx = x + kx - 1;
        if (xx < 0 || xx >= Ww) continue;
        c += patch[(size_t)(yy * Ww + xx) * Dd + d] * dw_w[d * 9 + ky * 3 + kx];
      }
    }
#pragma unroll
    for (int o = 0; o < 9; o++) acc[o] += c * pw_w[o * Dd + d];
  }

  __shared__ float sh[256 * 9];
#pragma unroll
  for (int o = 0; o < 9; o++) sh[tid * 9 + o] = acc[o];
  __syncthreads();
  for (int s = 128; s > 0; s >>= 1) {
    if (tid < s) {
      for (int o = 0; o < 9; o++) sh[tid * 9 + o] += sh[(tid + s) * 9 + o];
    }
    __syncthreads();
  }

  if (tid == 0) {
    float l[9], q[9];
    float mx = -INFINITY;
    for (int o = 0; o < 9; o++) {
      l[o] = sh[o] + pw_b[o];
      mx = fmaxf(mx, l[o]);
    }
    float ssum = 0.f;
    for (int o = 0; o < 9; o++) {
      q[o] = expf(l[o] - mx);
      ssum += q[o];
    }
    for (int o = 0; o < 9; o++) q[o] = q[o] / ssum;

    // accumulate into distinct clipped columns, ascending-o order
    int cols[9];
    float vals[9];
    int ncol = 0;
    for (int o = 0; o < 9; o++) {
      int dy = o / 3 - 1, dx = o % 3 - 1;
      int ny = min(max(y + dy, 0), Hh - 1);
      int nx = min(max(x + dx, 0), Ww - 1);
      int col = ny * Ww + nx;
      int f = -1;
      for (int j = 0; j < ncol; j++)
        if (cols[j] == col) { f = j; break; }
      if (f >= 0) vals[f] += q[o];
      else { cols[ncol] = col; vals[ncol] = q[o]; ncol++; }
    }
    // argmax, tie -> lowest column (all vals > 0, rest of row is 0)
    float best = -1.f;
    int bcol = 1 << 30;
    for (int j = 0; j < ncol; j++) {
      if (vals[j] > best || (vals[j] == best && cols[j] < bcol)) {
        best = vals[j];
        bcol = cols[j];
      }
    }
    ((int*)batch_base(outb, b))[R0_OFF + n] = bcol;
  }
}

// ---------------------------------------------------------------------------
// K2: 6x pointer jumping (r = r[r]) + counts + stable counting sort of tokens
//     by root (ascending token order within cluster == reference scatter
//     order). One block per batch, 576 threads.
// ---------------------------------------------------------------------------
__global__ __launch_bounds__(576) void cluster_kernel(float* __restrict__ outb) {
  int b = blockIdx.x;
  int n = threadIdx.x;
  int* base = (int*)batch_base(outb, b);
  __shared__ int ra[Nn], rb[Nn], scnt[Nn], soff[Nn];
  ra[n] = base[R0_OFF + n];
  scnt[n] = 0;
  __syncthreads();
  for (int it = 0; it < 6; it++) {
    rb[n] = ra[ra[n]];
    __syncthreads();
    ra[n] = rb[n];
    __syncthreads();
  }
  int r = ra[n];
  atomicAdd(&scnt[r], 1);
  __syncthreads();
  base[CNTS_OFF + n] = scnt[n];
  if (n == 0) {
    int run = 0;
    for (int i = 0; i < Nn; i++) {
      soff[i] = run;
      run += scnt[i];
    }
  }
  __syncthreads();
  base[OFFS_OFF + n] = soff[n];
  int rk = 0;
  for (int m = 0; m < n; m++) rk += (ra[m] == r);
  base[MEMB_OFF + soff[r] + rk] = n;
}

// ---------------------------------------------------------------------------
// K3: top-256 of counts with exact jax.lax.top_k tie semantics (value desc,
//     index asc), output in ascending index order (= sort(topk_idx)).
// ---------------------------------------------------------------------------
__global__ __launch_bounds__(576) void topk_counts_kernel(float* __restrict__ outb) {
  int b = blockIdx.x, n = threadIdx.x;
  int* base = (int*)batch_base(outb, b);
  __shared__ int sc[Nn];
  __shared__ int sel[Nn];
  sc[n] = base[CNTS_OFF + n];
  __syncthreads();
  int cn = sc[n];
  int rank = 0;
  for (int m = 0; m < Nn; m++) {
    int cm = sc[m];
    rank += (cm > cn) || (cm == cn && m < n);
  }
  sel[n] = (rank < Kk) ? 1 : 0;
  __syncthreads();
  if (sel[n]) {
    int pos = 0;
    for (int m = 0; m < n; m++) pos += sel[m];
    base[ORD_OFF + pos] = n;
    base[CNT_OFF + pos] = cn;
  }
}

// ---------------------------------------------------------------------------
// K4: qcls[b,d'] = cls[b]·q_w[d',:] + q_b[d']. One wave per d', loop b.
// ---------------------------------------------------------------------------
__global__ __launch_bounds__(64) void qcls_kernel(
    const float* __restrict__ tok2d, const float* __restrict__ q_w,
    const float* __restrict__ q_b, float* __restrict__ outb) {
  int dp = blockIdx.x;
  int lane = threadIdx.x;
  float qv[16];
#pragma unroll
  for (int i = 0; i < 16; i++) qv[i] = q_w[(size_t)dp * Dd + lane + 64 * i];
  float qb = q_b[dp];
  for (int b = 0; b < Bb; b++) {
    const float* cls = tok2d + (size_t)b * TOKSTRIDE;
    float a = 0.f;
#pragma unroll
    for (int i = 0; i < 16; i++) a += cls[lane + 64 * i] * qv[i];
#pragma unroll
    for (int s = 32; s > 0; s >>= 1) a += __shfl_down(a, s, 64);
    if (lane == 0) batch_base(outb, b)[QC_OFF + dp] = a + qb;
  }
}

// ---------------------------------------------------------------------------
// K5: u[b,d] = sum_d' qcls[b,d'] * v_w[d',d]  (coalesced over d)
// K6 fused: t[b] = qcls[b]·v_b  (done by block (b,0) wave 0 after u part? no —
//           keep separate simple kernel for clarity)
// ---------------------------------------------------------------------------
__global__ __launch_bounds__(256) void u_kernel(const float* __restrict__ v_w,
                                                float* __restrict__ outb) {
  int b = blockIdx.x >> 2;
  int d = (blockIdx.x & 3) * 256 + threadIdx.x;
  float* base = batch_base(outb, b);
  __shared__ float qs[Dd];
  for (int i = threadIdx.x; i < Dd; i += 256) qs[i] = base[QC_OFF + i];
  __syncthreads();
  float a = 0.f;
#pragma unroll 4
  for (int dp = 0; dp < Dd; dp++) a += qs[dp] * v_w[(size_t)dp * Dd + d];
  base[U_OFF + d] = a;
}

__global__ __launch_bounds__(256) void t_kernel(const float* __restrict__ v_b,
                                                float* __restrict__ outb) {
  int b = blockIdx.x;
  int tid = threadIdx.x;
  float* base = batch_base(outb, b);
  float a = 0.f;
  for (int i = tid; i < Dd; i += 256) a += base[QC_OFF + i] * v_b[i];
  __shared__ float sh[256];
  sh[tid] = a;
  __syncthreads();
  for (int s = 128; s > 0; s >>= 1) {
    if (tid < s) sh[tid] += sh[tid + s];
    __syncthreads();
  }
  if (tid == 0) base[T_OFF] = sh[0];
}

// ---------------------------------------------------------------------------
// K7: p[b,n] = patch[b,n]·u[b]
// ---------------------------------------------------------------------------
__global__ __launch_bounds__(256) void ptok_kernel(
    const float* __restrict__ tok2d, float* __restrict__ outb) {
  int blk = blockIdx.x;
  int b = blk / Nn, n = blk % Nn;
  int tid = threadIdx.x;
  float* base = batch_base(outb, b);
  const float* row = tok2d + (size_t)b * TOKSTRIDE + (size_t)(1 + n) * Dd;
  float a = 0.f;
#pragma unroll
  for (int i = 0; i < 4; i++)
    a += row[tid + 256 * i] * base[U_OFF + tid + 256 * i];
  __shared__ float sh[256];
  sh[tid] = a;
  __syncthreads();
  for (int s = 128; s > 0; s >>= 1) {
    if (tid < s) sh[tid] += sh[tid + s];
    __syncthreads();
  }
  if (tid == 0) base[P_OFF + n] = sh[0];
}

// ---------------------------------------------------------------------------
// K8: scores[b,k] = ((sum_{members} p)/cnt + t[b]) / 32,  -inf when cnt==0
// ---------------------------------------------------------------------------
__global__ __launch_bounds__(256) void scores_kernel(float* __restrict__ outb) {
  int b = blockIdx.x;
  int k = threadIdx.x;  // block == Kk
  float* basef = batch_base(outb, b);
  int* base = (int*)basef;
  int idx = base[ORD_OFF + k];
  int c = base[CNT_OFF + k];
  float s;
  if (c > 0) {
    int off = base[OFFS_OFF + idx];
    float sum = 0.f;
    for (int j = 0; j < c; j++) sum += basef[P_OFF + base[MEMB_OFF + off + j]];
    s = (sum / (float)c + basef[T_OFF]) * (1.0f / 32.0f);
  } else {
    s = -INFINITY;
  }
  basef[SC_OFF + k] = s;
}

// ---------------------------------------------------------------------------
// K9: top-128 of 256 scores, exact top_k tie semantics, ascending order out.
// ---------------------------------------------------------------------------
__global__ __launch_bounds__(256) void topk_scores_kernel(float* __restrict__ outb) {
  int b = blockIdx.x;
  int k = threadIdx.x;
  float* basef = batch_base(outb, b);
  int* base = (int*)basef;
  __shared__ float ss[Kk];
  __shared__ int sel[Kk];
  ss[k] = basef[SC_OFF + k];
  __syncthreads();
  float vk = ss[k];
  int rank = 0;
  for (int m = 0; m < Kk; m++) {
    float vm = ss[m];
    rank += (vm > vk) || (vm == vk && m < k);
  }
  sel[k] = (rank < Mm) ? 1 : 0;
  __syncthreads();
  if (sel[k]) {
    int pos = 0;
    for (int m = 0; m < k; m++) pos += sel[m];
    base[OUTI_OFF + pos] = k;
  }
}

// ---------------------------------------------------------------------------
// K10: plan kernel. One block per batch. Loads ALL gather metadata for this
// batch into LDS (syncthreads), THEN writes per-row plans [count, members...]
// into each of the batch's 128 output rows (overwriting the scratch safely —
// only this block touches this batch's rows).
// ---------------------------------------------------------------------------
__global__ __launch_bounds__(256) void plan_kernel(float* __restrict__ outb) {
  int b = blockIdx.x;
  int tid = threadIdx.x;
  int* base = (int*)batch_base(outb, b);
  __shared__ int s_mem[Nn], s_off[Nn], s_ord[Kk], s_cnt[Kk], s_out[Mm];
  for (int i = tid; i < Nn; i += 256) {
    s_mem[i] = base[MEMB_OFF + i];
    s_off[i] = base[OFFS_OFF + i];
  }
  s_ord[tid] = base[ORD_OFF + tid];
  s_cnt[tid] = base[CNT_OFF + tid];
  if (tid < Mm) s_out[tid] = base[OUTI_OFF + tid];
  __syncthreads();
  for (int kp = 0; kp < Mm; kp++) {
    int k = s_out[kp];
    int idx = s_ord[k];
    int c = s_cnt[k];
    int off = s_off[idx];
    int* row = base + kp * Dd;
    if (tid == 0) row[0] = c;
    for (int j = tid; j < c; j += 256) row[1 + j] = s_mem[off + j];
  }
}

// ---------------------------------------------------------------------------
// K11: output. One block per output row; reads its OWN row's plan into LDS,
// then overwrites the row with the cluster mean (members in ascending token
// order == reference scatter-add order).
// ---------------------------------------------------------------------------
__global__ __launch_bounds__(256) void output_kernel(
    const float* __restrict__ tok2d, float* __restrict__ outb) {
  int blk = blockIdx.x;  // b*Mm + kp
  int b = blk / Mm;
  int tid = threadIdx.x;
  float* rowf = outb + (size_t)blk * Dd;
  int* rowi = (int*)rowf;
  __shared__ int s_c;
  __shared__ int s_m[Nn];
  if (tid == 0) s_c = rowi[0];
  __syncthreads();
  int c = s_c;
  for (int j = tid; j < c; j += 256) s_m[j] = rowi[1 + j];
  __syncthreads();
  const float* patch = tok2d + (size_t)b * TOKSTRIDE + Dd;
  float acc[4] = {0.f, 0.f, 0.f, 0.f};
  for (int j = 0; j < c; j++) {
    const float* r = patch + (size_t)s_m[j] * Dd;
#pragma unroll
    for (int i = 0; i < 4; i++) acc[i] += r[tid + 256 * i];
  }
  float cdiv = (float)max(c, 1);
#pragma unroll
  for (int i = 0; i < 4; i++) rowf[tid + 256 * i] = acc[i] / cdiv;
}

// ---------------------------------------------------------------------------
extern "C" void kernel_launch(void* const* d_in, const int* in_sizes, int n_in,
                              void* d_out, int out_size, void* d_ws,
                              size_t ws_size, hipStream_t stream) {
  const float* tok2d = (const float*)d_in[0];
  const float* dw_w = (const float*)d_in[1];
  const float* pw_w = (const float*)d_in[2];
  const float* pw_b = (const float*)d_in[3];
  const float* q_w = (const float*)d_in[4];
  const float* q_b = (const float*)d_in[5];
  const float* v_w = (const float*)d_in[6];
  const float* v_b = (const float*)d_in[7];
  float* out = (float*)d_out;
  (void)d_ws; (void)ws_size;  // d_ws intentionally unused (size unknown)

  affinity_root_kernel<<<dim3(Bb * Nn), dim3(256), 0, stream>>>(
      tok2d, dw_w, pw_w, pw_b, out);
  cluster_kernel<<<dim3(Bb), dim3(Nn), 0, stream>>>(out);
  topk_counts_kernel<<<dim3(Bb), dim3(Nn), 0, stream>>>(out);
  qcls_kernel<<<dim3(Dd), dim3(64), 0, stream>>>(tok2d, q_w, q_b, out);
  u_kernel<<<dim3(Bb * 4), dim3(256), 0, stream>>>(v_w, out);
  t_kernel<<<dim3(Bb), dim3(256), 0, stream>>>(v_b, out);
  ptok_kernel<<<dim3(Bb * Nn), dim3(256), 0, stream>>>(tok2d, out);
  scores_kernel<<<dim3(Bb), dim3(Kk), 0, stream>>>(out);
  topk_scores_kernel<<<dim3(Bb), dim3(Kk), 0, stream>>>(out);
  plan_kernel<<<dim3(Bb), dim3(256), 0, stream>>>(out);
  output_kernel<<<dim3(Bb * Mm), dim3(256), 0, stream>>>(tok2d, out);
}

// Round 3
// 450.865 us; speedup vs baseline: 1.3145x; 1.3145x over previous
//
#include <hip/hip_runtime.h>
#include <math.h>

#define Hh 24
#define Ww 24
#define Nn 576
#define Dd 1024
#define Bb 32
#define Kk 256
#define Mm 128
#define TOKSTRIDE (577 * 1024)

// Per-batch scratch lives INSIDE d_out: batch b owns out[b*Mm*Dd .. (b+1)*Mm*Dd).
// Scratch is consumed (via LDS/regs) before those rows are overwritten by the
// plan/output kernels. d_ws is NOT used.
#define R0_OFF 0      // roots0           : 576 int
#define MEMB_OFF 1152 // members (sorted) : 576 int
#define OFFS_OFF 1728 // offsets per root : 576 int
#define ORD_OFF 2304  // ord_idx (top-256): 256 int
#define CNT_OFF 2560  // cnt_sel          : 256 int
#define P_OFF 2944    // p = patch.u      : 576 float
#define QC_OFF 3776   // qcls             : 1024 float
#define U_OFF 4800    // u = qcls.v_w     : 1024 float
#define T_OFF 5824    // t = qcls.v_b     : 1 float
#define UP_OFF 6144   // u partials       : 8*1024 float  (ends 14336 < 131072)

__device__ __forceinline__ float* batch_base(float* out, int b) {
  return out + (size_t)b * Mm * Dd;
}

// ---------------------------------------------------------------------------
// K1: depthwise 3x3 conv (SAME, zero pad) + pointwise 9xD + softmax over 9
//     + duplicate-accumulated clipped-neighbor affinity + argmax (tie ->
//     lowest col) => roots0. ONE WAVE per (b,n); 4 waves/block; float4 loads;
//     in-wave shuffle reduction (no LDS, no syncthreads).
// ---------------------------------------------------------------------------
__global__ __launch_bounds__(256) void affinity_root_kernel(
    const float* __restrict__ tok2d, const float* __restrict__ dw_w,
    const float* __restrict__ pw_w, const float* __restrict__ pw_b,
    float* __restrict__ outb) {
  int wave = threadIdx.x >> 6;
  int lane = threadIdx.x & 63;
  int gid = blockIdx.x * 4 + wave;  // [0, Bb*Nn)
  int b = gid / Nn, n = gid % Nn;
  int y = n / Ww, x = n % Ww;
  const float* patch = tok2d + (size_t)b * TOKSTRIDE + Dd;  // skip cls token

  float acc[9];
#pragma unroll
  for (int o = 0; o < 9; o++) acc[o] = 0.f;

#pragma unroll
  for (int i = 0; i < 4; i++) {
    int d0 = lane * 4 + 256 * i;
    // depthwise weights for 4 channels: 36 consecutive floats, 144B-aligned
    union { float4 v[9]; float f[36]; } w;
    const float4* dwp = (const float4*)(dw_w + (size_t)d0 * 9);
#pragma unroll
    for (int j = 0; j < 9; j++) w.v[j] = dwp[j];

    // 3x3 neighborhood (zero pad), float4 per position
    float4 pv[9];
#pragma unroll
    for (int ky = 0; ky < 3; ky++) {
      int yy = y + ky - 1;
#pragma unroll
      for (int kx = 0; kx < 3; kx++) {
        int xx = x + kx - 1;
        int k = ky * 3 + kx;
        if (yy >= 0 && yy < Hh && xx >= 0 && xx < Ww) {
          pv[k] = *(const float4*)(patch + (size_t)(yy * Ww + xx) * Dd + d0);
        } else {
          pv[k] = make_float4(0.f, 0.f, 0.f, 0.f);
        }
      }
    }

    float4 cc = make_float4(0.f, 0.f, 0.f, 0.f);
#pragma unroll
    for (int k = 0; k < 9; k++) {
      cc.x += pv[k].x * w.f[k];
      cc.y += pv[k].y * w.f[9 + k];
      cc.z += pv[k].z * w.f[18 + k];
      cc.w += pv[k].w * w.f[27 + k];
    }

#pragma unroll
    for (int o = 0; o < 9; o++) {
      float4 pwv = *(const float4*)(pw_w + (size_t)o * Dd + d0);
      acc[o] += cc.x * pwv.x + cc.y * pwv.y + cc.z * pwv.z + cc.w * pwv.w;
    }
  }

  // in-wave reduction of 9 accumulators
#pragma unroll
  for (int s = 32; s > 0; s >>= 1) {
#pragma unroll
    for (int o = 0; o < 9; o++) acc[o] += __shfl_down(acc[o], s, 64);
  }

  if (lane == 0) {
    float q[9];
    float mx = -INFINITY;
#pragma unroll
    for (int o = 0; o < 9; o++) {
      acc[o] += pw_b[o];
      mx = fmaxf(mx, acc[o]);
    }
    float ssum = 0.f;
#pragma unroll
    for (int o = 0; o < 9; o++) {
      q[o] = expf(acc[o] - mx);
      ssum += q[o];
    }
#pragma unroll
    for (int o = 0; o < 9; o++) q[o] = q[o] / ssum;

    // accumulate into distinct clipped columns, ascending-o order
    int cols[9];
    float vals[9];
    int ncol = 0;
    for (int o = 0; o < 9; o++) {
      int dy = o / 3 - 1, dx = o % 3 - 1;
      int ny = min(max(y + dy, 0), Hh - 1);
      int nx = min(max(x + dx, 0), Ww - 1);
      int col = ny * Ww + nx;
      int f = -1;
      for (int j = 0; j < ncol; j++)
        if (cols[j] == col) { f = j; break; }
      if (f >= 0) vals[f] += q[o];
      else { cols[ncol] = col; vals[ncol] = q[o]; ncol++; }
    }
    // argmax, tie -> lowest column (all vals > 0, rest of row is 0)
    float best = -1.f;
    int bcol = 1 << 30;
    for (int j = 0; j < ncol; j++) {
      if (vals[j] > best || (vals[j] == best && cols[j] < bcol)) {
        best = vals[j];
        bcol = cols[j];
      }
    }
    ((int*)batch_base(outb, b))[R0_OFF + n] = bcol;
  }
}

// ---------------------------------------------------------------------------
// K2: 6x pointer jumping + counts + stable counting sort + top-256 of counts
//     (exact jax.lax.top_k tie semantics), fused. One block/batch, 576 thr.
// ---------------------------------------------------------------------------
__global__ __launch_bounds__(576) void cluster_topk_kernel(float* __restrict__ outb) {
  int b = blockIdx.x;
  int n = threadIdx.x;
  int* base = (int*)batch_base(outb, b);
  __shared__ int ra[Nn], rb[Nn], scnt[Nn], soff[Nn];
  ra[n] = base[R0_OFF + n];
  scnt[n] = 0;
  __syncthreads();
  for (int it = 0; it < 6; it++) {
    rb[n] = ra[ra[n]];
    __syncthreads();
    ra[n] = rb[n];
    __syncthreads();
  }
  int r = ra[n];
  atomicAdd(&scnt[r], 1);
  __syncthreads();
  if (n == 0) {
    int run = 0;
    for (int i = 0; i < Nn; i++) {
      soff[i] = run;
      run += scnt[i];
    }
  }
  __syncthreads();
  base[OFFS_OFF + n] = soff[n];
  int rk = 0;
  for (int m = 0; m < n; m++) rk += (ra[m] == r);
  base[MEMB_OFF + soff[r] + rk] = n;

  // --- top-256 of counts (value desc, index asc), ascending-index output ---
  int cn = scnt[n];
  int rank = 0;
  for (int m = 0; m < Nn; m++) {
    int cm = scnt[m];
    rank += (cm > cn) || (cm == cn && m < n);
  }
  rb[n] = (rank < Kk) ? 1 : 0;  // reuse rb as sel
  __syncthreads();
  if (rb[n]) {
    int pos = 0;
    for (int m = 0; m < n; m++) pos += rb[m];
    base[ORD_OFF + pos] = n;
    base[CNT_OFF + pos] = cn;
  }
}

// ---------------------------------------------------------------------------
// K3: qcls[b,dp] = cls[b]·q_w[dp,:] + q_b[dp]. One block per dp; 4 waves,
//     each handles 8 batches (q_w row reused in regs, L1 across waves).
// ---------------------------------------------------------------------------
__global__ __launch_bounds__(256) void qcls_kernel(
    const float* __restrict__ tok2d, const float* __restrict__ q_w,
    const float* __restrict__ q_b, float* __restrict__ outb) {
  int dp = blockIdx.x;
  int wave = threadIdx.x >> 6;
  int lane = threadIdx.x & 63;
  float4 qv[4];
#pragma unroll
  for (int i = 0; i < 4; i++)
    qv[i] = *(const float4*)(q_w + (size_t)dp * Dd + lane * 4 + 256 * i);
  float qb = q_b[dp];
  for (int bb = 0; bb < 8; bb++) {
    int b = wave * 8 + bb;
    const float* cls = tok2d + (size_t)b * TOKSTRIDE;
    float a = 0.f;
#pragma unroll
    for (int i = 0; i < 4; i++) {
      float4 cv = *(const float4*)(cls + lane * 4 + 256 * i);
      a += qv[i].x * cv.x + qv[i].y * cv.y + qv[i].z * cv.z + qv[i].w * cv.w;
    }
#pragma unroll
    for (int s = 32; s > 0; s >>= 1) a += __shfl_down(a, s, 64);
    if (lane == 0) batch_base(outb, b)[QC_OFF + dp] = a + qb;
  }
}

// ---------------------------------------------------------------------------
// K4: u partials: up[chunk][d] = sum_{dp in chunk} qcls[dp] * v_w[dp,d].
//     Grid = 32 b x 8 chunks = 256 blocks; float4 over d.
// ---------------------------------------------------------------------------
__global__ __launch_bounds__(256) void u_part_kernel(const float* __restrict__ v_w,
                                                     float* __restrict__ outb) {
  int b = blockIdx.x >> 3;
  int chunk = blockIdx.x & 7;
  int tid = threadIdx.x;
  int d0 = tid * 4;
  float* basef = batch_base(outb, b);
  __shared__ float qs[128];
  if (tid < 128) qs[tid] = basef[QC_OFF + chunk * 128 + tid];
  __syncthreads();
  float4 a = make_float4(0.f, 0.f, 0.f, 0.f);
#pragma unroll 4
  for (int dpl = 0; dpl < 128; dpl++) {
    int dp = chunk * 128 + dpl;
    float4 vv = *(const float4*)(v_w + (size_t)dp * Dd + d0);
    float qq = qs[dpl];
    a.x += qq * vv.x; a.y += qq * vv.y; a.z += qq * vv.z; a.w += qq * vv.w;
  }
  *(float4*)(basef + UP_OFF + chunk * Dd + d0) = a;
}

// ---------------------------------------------------------------------------
// K5: combine u partials + t[b] = qcls[b]·v_b. One block per batch.
// ---------------------------------------------------------------------------
__global__ __launch_bounds__(256) void combine_ut_kernel(
    const float* __restrict__ v_b, float* __restrict__ outb) {
  int b = blockIdx.x;
  int tid = threadIdx.x;
  float* basef = batch_base(outb, b);
  int d0 = tid * 4;
  float4 s = make_float4(0.f, 0.f, 0.f, 0.f);
#pragma unroll
  for (int c = 0; c < 8; c++) {
    float4 v = *(const float4*)(basef + UP_OFF + c * Dd + d0);
    s.x += v.x; s.y += v.y; s.z += v.z; s.w += v.w;
  }
  *(float4*)(basef + U_OFF + d0) = s;

  float a = 0.f;
  for (int i = tid; i < Dd; i += 256) a += basef[QC_OFF + i] * v_b[i];
  __shared__ float sh[256];
  sh[tid] = a;
  __syncthreads();
  for (int st = 128; st > 0; st >>= 1) {
    if (tid < st) sh[tid] += sh[tid + st];
    __syncthreads();
  }
  if (tid == 0) basef[T_OFF] = sh[0];
}

// ---------------------------------------------------------------------------
// K6: p[b,n] = patch[b,n]·u[b]. One wave per (b,n); float4; shuffle reduce.
// ---------------------------------------------------------------------------
__global__ __launch_bounds__(256) void ptok_kernel(
    const float* __restrict__ tok2d, float* __restrict__ outb) {
  int wave = threadIdx.x >> 6;
  int lane = threadIdx.x & 63;
  int gid = blockIdx.x * 4 + wave;
  int b = gid / Nn, n = gid % Nn;
  float* basef = batch_base(outb, b);
  const float* row = tok2d + (size_t)b * TOKSTRIDE + (size_t)(1 + n) * Dd;
  float a = 0.f;
#pragma unroll
  for (int i = 0; i < 4; i++) {
    float4 rv = *(const float4*)(row + lane * 4 + 256 * i);
    float4 uv = *(const float4*)(basef + U_OFF + lane * 4 + 256 * i);
    a += rv.x * uv.x + rv.y * uv.y + rv.z * uv.z + rv.w * uv.w;
  }
#pragma unroll
  for (int s = 32; s > 0; s >>= 1) a += __shfl_down(a, s, 64);
  if (lane == 0) basef[P_OFF + n] = a;
}

// ---------------------------------------------------------------------------
// K7: scores + top-128 (exact top_k ties) + per-row plan write, fused.
//     One block per batch, 256 threads. All metadata staged to LDS before
//     the plan phase overwrites the batch's output rows.
// ---------------------------------------------------------------------------
__global__ __launch_bounds__(256) void scores_plan_kernel(float* __restrict__ outb) {
  int b = blockIdx.x;
  int tid = threadIdx.x;
  float* basef = batch_base(outb, b);
  int* base = (int*)basef;
  __shared__ int s_mem[Nn], s_off[Nn], s_ord[Kk], s_cnt[Kk], s_out[Mm];
  __shared__ float ss[Kk];
  __shared__ int sel[Kk];
  for (int i = tid; i < Nn; i += 256) {
    s_mem[i] = base[MEMB_OFF + i];
    s_off[i] = base[OFFS_OFF + i];
  }
  s_ord[tid] = base[ORD_OFF + tid];
  s_cnt[tid] = base[CNT_OFF + tid];
  float tt = basef[T_OFF];
  __syncthreads();

  // scores
  int idx = s_ord[tid];
  int c = s_cnt[tid];
  float s;
  if (c > 0) {
    int off = s_off[idx];
    float sum = 0.f;
    for (int j = 0; j < c; j++) sum += basef[P_OFF + s_mem[off + j]];
    s = (sum / (float)c + tt) * (1.0f / 32.0f);
  } else {
    s = -INFINITY;
  }
  ss[tid] = s;
  __syncthreads();

  // top-128 (value desc, index asc), ascending-index output
  float vk = ss[tid];
  int rank = 0;
  for (int m = 0; m < Kk; m++) {
    float vm = ss[m];
    rank += (vm > vk) || (vm == vk && m < tid);
  }
  sel[tid] = (rank < Mm) ? 1 : 0;
  __syncthreads();
  if (sel[tid]) {
    int pos = 0;
    for (int m = 0; m < tid; m++) pos += sel[m];
    s_out[pos] = tid;
  }
  __syncthreads();

  // plan: write [count, member ids...] into each of this batch's 128 rows
  for (int kp = 0; kp < Mm; kp++) {
    int k = s_out[kp];
    int kidx = s_ord[k];
    int kc = s_cnt[k];
    int koff = s_off[kidx];
    int* row = base + kp * Dd;
    if (tid == 0) row[0] = kc;
    for (int j = tid; j < kc; j += 256) row[1 + j] = s_mem[koff + j];
  }
}

// ---------------------------------------------------------------------------
// K8: output. One block per output row; reads its OWN row's plan into LDS,
//     then overwrites the row with the cluster mean. float4 over d.
// ---------------------------------------------------------------------------
__global__ __launch_bounds__(256) void output_kernel(
    const float* __restrict__ tok2d, float* __restrict__ outb) {
  int blk = blockIdx.x;  // b*Mm + kp
  int b = blk / Mm;
  int tid = threadIdx.x;
  float* rowf = outb + (size_t)blk * Dd;
  int* rowi = (int*)rowf;
  __shared__ int s_c;
  __shared__ int s_m[Nn];
  if (tid == 0) s_c = rowi[0];
  __syncthreads();
  int c = s_c;
  for (int j = tid; j < c; j += 256) s_m[j] = rowi[1 + j];
  __syncthreads();
  const float* patch = tok2d + (size_t)b * TOKSTRIDE + Dd;
  int d0 = tid * 4;
  float4 acc = make_float4(0.f, 0.f, 0.f, 0.f);
  for (int j = 0; j < c; j++) {
    float4 rv = *(const float4*)(patch + (size_t)s_m[j] * Dd + d0);
    acc.x += rv.x; acc.y += rv.y; acc.z += rv.z; acc.w += rv.w;
  }
  float inv = 1.0f / (float)max(c, 1);
  *(float4*)(rowf + d0) =
      make_float4(acc.x * inv, acc.y * inv, acc.z * inv, acc.w * inv);
}

// ---------------------------------------------------------------------------
extern "C" void kernel_launch(void* const* d_in, const int* in_sizes, int n_in,
                              void* d_out, int out_size, void* d_ws,
                              size_t ws_size, hipStream_t stream) {
  const float* tok2d = (const float*)d_in[0];
  const float* dw_w = (const float*)d_in[1];
  const float* pw_w = (const float*)d_in[2];
  const float* pw_b = (const float*)d_in[3];
  const float* q_w = (const float*)d_in[4];
  const float* q_b = (const float*)d_in[5];
  const float* v_w = (const float*)d_in[6];
  const float* v_b = (const float*)d_in[7];
  float* out = (float*)d_out;
  (void)d_ws; (void)ws_size;  // d_ws intentionally unused

  affinity_root_kernel<<<dim3(Bb * Nn / 4), dim3(256), 0, stream>>>(
      tok2d, dw_w, pw_w, pw_b, out);
  cluster_topk_kernel<<<dim3(Bb), dim3(Nn), 0, stream>>>(out);
  qcls_kernel<<<dim3(Dd), dim3(256), 0, stream>>>(tok2d, q_w, q_b, out);
  u_part_kernel<<<dim3(Bb * 8), dim3(256), 0, stream>>>(v_w, out);
  combine_ut_kernel<<<dim3(Bb), dim3(256), 0, stream>>>(v_b, out);
  ptok_kernel<<<dim3(Bb * Nn / 4), dim3(256), 0, stream>>>(tok2d, out);
  scores_plan_kernel<<<dim3(Bb), dim3(256), 0, stream>>>(out);
  output_kernel<<<dim3(Bb * Mm), dim3(256), 0, stream>>>(tok2d, out);
}

// Round 4
// 334.831 us; speedup vs baseline: 1.7700x; 1.3465x over previous
//
#include <hip/hip_runtime.h>
#include <math.h>

#define Hh 24
#define Ww 24
#define Nn 576
#define Dd 1024
#define Bb 32
#define Kk 256
#define Mm 128
#define TOKSTRIDE (577 * 1024)

// Per-batch scratch lives INSIDE d_out: batch b owns out[b*Mm*Dd .. (b+1)*Mm*Dd).
// Scratch is consumed (via LDS/regs) before the plan/output kernels overwrite
// the rows. d_ws is NOT used.
#define R0_OFF 0       // roots0           : 576 int
#define MEMB_OFF 1152  // members (sorted) : 576 int
#define OFFS_OFF 1728  // offsets per root : 576 int
#define ORD_OFF 2304   // ord_idx (top-256): 256 int
#define CNT_OFF 2560   // cnt_sel          : 256 int
#define P_OFF 2944     // p = patch.u      : 576 float
#define QC_OFF 3776    // qcls             : 1024 float
#define U_OFF 4800     // u = qcls.v_w     : 1024 float
#define T_OFF 5824     // t = qcls.v_b     : 1 float
#define UP_OFF 6144    // u partials       : 8*1024 float (ends 14336)
#define PART_OFF 16384 // affinity partials: 576*36 float (ends 37120 < 131072)

__device__ __forceinline__ float* batch_base(float* out, int b) {
  return out + (size_t)b * Mm * Dd;
}

// ---------------------------------------------------------------------------
// K1a: affinity partials. ONE WAVE per (token, d-chunk of 256): depthwise 3x3
//      (zero pad) + pointwise 9xD partial logits, shuffle-reduced, 9 floats
//      out. 4 waves/block share a token (L1 reuse of the 9 patch rows).
//      launch_bounds(256,4) caps VGPR at 128 for >=16 waves/CU.
// ---------------------------------------------------------------------------
__global__ __launch_bounds__(256, 4) void affinity_part_kernel(
    const float* __restrict__ tok2d, const float* __restrict__ dw_w,
    const float* __restrict__ pw_w, float* __restrict__ outb) {
  int wave = threadIdx.x >> 6;  // = d-chunk
  int lane = threadIdx.x & 63;
  int tok = blockIdx.x;  // [0, Bb*Nn)
  int b = tok / Nn, n = tok % Nn;
  int y = n / Ww, x = n % Ww;
  int d0 = wave * 256 + lane * 4;
  const float* patch = tok2d + (size_t)b * TOKSTRIDE + Dd;  // skip cls token

  // depthwise weights for 4 channels: 36 consecutive floats, 16B-aligned
  union { float4 v[9]; float f[36]; } w;
  const float4* dwp = (const float4*)(dw_w + (size_t)d0 * 9);
#pragma unroll
  for (int j = 0; j < 9; j++) w.v[j] = dwp[j];

  // 3x3 neighborhood (zero pad), float4 per position
  float4 pv[9];
#pragma unroll
  for (int ky = 0; ky < 3; ky++) {
    int yy = y + ky - 1;
#pragma unroll
    for (int kx = 0; kx < 3; kx++) {
      int xx = x + kx - 1;
      int k = ky * 3 + kx;
      if (yy >= 0 && yy < Hh && xx >= 0 && xx < Ww)
        pv[k] = *(const float4*)(patch + (size_t)(yy * Ww + xx) * Dd + d0);
      else
        pv[k] = make_float4(0.f, 0.f, 0.f, 0.f);
    }
  }

  float4 cc = make_float4(0.f, 0.f, 0.f, 0.f);
#pragma unroll
  for (int k = 0; k < 9; k++) {
    cc.x += pv[k].x * w.f[k];
    cc.y += pv[k].y * w.f[9 + k];
    cc.z += pv[k].z * w.f[18 + k];
    cc.w += pv[k].w * w.f[27 + k];
  }

  float acc[9];
#pragma unroll
  for (int o = 0; o < 9; o++) {
    float4 pwv = *(const float4*)(pw_w + (size_t)o * Dd + d0);
    acc[o] = cc.x * pwv.x + cc.y * pwv.y + cc.z * pwv.z + cc.w * pwv.w;
  }

#pragma unroll
  for (int s = 32; s > 0; s >>= 1) {
#pragma unroll
    for (int o = 0; o < 9; o++) acc[o] += __shfl_down(acc[o], s, 64);
  }

  if (lane == 0) {
    float* part = batch_base(outb, b) + PART_OFF + (size_t)n * 36 + wave * 9;
#pragma unroll
    for (int o = 0; o < 9; o++) part[o] = acc[o];
  }
}

// ---------------------------------------------------------------------------
// K1b: finalize affinity. One thread per token: sum 4 partials + bias,
//      softmax, duplicate-accumulated clipped-neighbor argmax (tie -> lowest
//      col) => roots0.
// ---------------------------------------------------------------------------
__global__ __launch_bounds__(256) void affinity_fin_kernel(
    const float* __restrict__ pw_b, float* __restrict__ outb) {
  int gid = blockIdx.x * 256 + threadIdx.x;  // [0, Bb*Nn)
  int b = gid / Nn, n = gid % Nn;
  int y = n / Ww, x = n % Ww;
  const float* part = batch_base(outb, b) + PART_OFF + (size_t)n * 36;
  float l[9], q[9];
  float mx = -INFINITY;
#pragma unroll
  for (int o = 0; o < 9; o++) {
    l[o] = part[o] + part[9 + o] + part[18 + o] + part[27 + o] + pw_b[o];
    mx = fmaxf(mx, l[o]);
  }
  float ssum = 0.f;
#pragma unroll
  for (int o = 0; o < 9; o++) {
    q[o] = expf(l[o] - mx);
    ssum += q[o];
  }
#pragma unroll
  for (int o = 0; o < 9; o++) q[o] = q[o] / ssum;

  // accumulate into distinct clipped columns, ascending-o order
  int cols[9];
  float vals[9];
  int ncol = 0;
  for (int o = 0; o < 9; o++) {
    int dy = o / 3 - 1, dx = o % 3 - 1;
    int ny = min(max(y + dy, 0), Hh - 1);
    int nx = min(max(x + dx, 0), Ww - 1);
    int col = ny * Ww + nx;
    int f = -1;
    for (int j = 0; j < ncol; j++)
      if (cols[j] == col) { f = j; break; }
    if (f >= 0) vals[f] += q[o];
    else { cols[ncol] = col; vals[ncol] = q[o]; ncol++; }
  }
  // argmax, tie -> lowest column (all vals > 0, rest of row is 0)
  float best = -1.f;
  int bcol = 1 << 30;
  for (int j = 0; j < ncol; j++) {
    if (vals[j] > best || (vals[j] == best && cols[j] < bcol)) {
      best = vals[j];
      bcol = cols[j];
    }
  }
  ((int*)batch_base(outb, b))[R0_OFF + n] = bcol;
}

// ---------------------------------------------------------------------------
// K2: 6x pointer jumping + counts + stable counting sort + top-256 of counts
//     (exact jax.lax.top_k tie semantics), fused. One block/batch, 576 thr.
//     Prefix sums via parallel Hillis-Steele scans (no serial thread-0 loop).
// ---------------------------------------------------------------------------
__global__ __launch_bounds__(576) void cluster_topk_kernel(float* __restrict__ outb) {
  int b = blockIdx.x;
  int n = threadIdx.x;
  int* base = (int*)batch_base(outb, b);
  __shared__ int ra[Nn], rb[Nn], scnt[Nn], soff[Nn];
  ra[n] = base[R0_OFF + n];
  scnt[n] = 0;
  __syncthreads();
  for (int it = 0; it < 6; it++) {
    rb[n] = ra[ra[n]];
    __syncthreads();
    ra[n] = rb[n];
    __syncthreads();
  }
  int r = ra[n];
  atomicAdd(&scnt[r], 1);
  __syncthreads();

  // inclusive scan of scnt -> soff
  soff[n] = scnt[n];
  __syncthreads();
  for (int s = 1; s < Nn; s <<= 1) {
    int v = (n >= s) ? soff[n - s] : 0;
    __syncthreads();
    soff[n] += v;
    __syncthreads();
  }
  int excl = soff[n] - scnt[n];
  base[OFFS_OFF + n] = excl;
  int offr = soff[r] - scnt[r];
  int rk = 0;
  for (int m = 0; m < n; m++) rk += (ra[m] == r);
  base[MEMB_OFF + offr + rk] = n;

  // --- top-256 of counts (value desc, index asc), ascending-index output ---
  int cn = scnt[n];
  int rank = 0;
  for (int m = 0; m < Nn; m++) {
    int cm = scnt[m];
    rank += (cm > cn) || (cm == cn && m < n);
  }
  int sl = (rank < Kk) ? 1 : 0;
  rb[n] = sl;
  __syncthreads();
  // inclusive scan of sel in rb
  for (int s = 1; s < Nn; s <<= 1) {
    int v = (n >= s) ? rb[n - s] : 0;
    __syncthreads();
    rb[n] += v;
    __syncthreads();
  }
  if (sl) {
    int pos = rb[n] - 1;
    base[ORD_OFF + pos] = n;
    base[CNT_OFF + pos] = cn;
  }
}

// ---------------------------------------------------------------------------
// K3: qcls[b,dp] = cls[b]·q_w[dp,:] + q_b[dp]. One block per dp; 4 waves,
//     each handles 8 batches (q_w row reused in regs).
// ---------------------------------------------------------------------------
__global__ __launch_bounds__(256) void qcls_kernel(
    const float* __restrict__ tok2d, const float* __restrict__ q_w,
    const float* __restrict__ q_b, float* __restrict__ outb) {
  int dp = blockIdx.x;
  int wave = threadIdx.x >> 6;
  int lane = threadIdx.x & 63;
  float4 qv[4];
#pragma unroll
  for (int i = 0; i < 4; i++)
    qv[i] = *(const float4*)(q_w + (size_t)dp * Dd + lane * 4 + 256 * i);
  float qb = q_b[dp];
  for (int bb = 0; bb < 8; bb++) {
    int b = wave * 8 + bb;
    const float* cls = tok2d + (size_t)b * TOKSTRIDE;
    float a = 0.f;
#pragma unroll
    for (int i = 0; i < 4; i++) {
      float4 cv = *(const float4*)(cls + lane * 4 + 256 * i);
      a += qv[i].x * cv.x + qv[i].y * cv.y + qv[i].z * cv.z + qv[i].w * cv.w;
    }
#pragma unroll
    for (int s = 32; s > 0; s >>= 1) a += __shfl_down(a, s, 64);
    if (lane == 0) batch_base(outb, b)[QC_OFF + dp] = a + qb;
  }
}

// ---------------------------------------------------------------------------
// K4: u partials: up[chunk][d] = sum_{dp in chunk} qcls[dp] * v_w[dp,d].
// ---------------------------------------------------------------------------
__global__ __launch_bounds__(256) void u_part_kernel(const float* __restrict__ v_w,
                                                     float* __restrict__ outb) {
  int b = blockIdx.x >> 3;
  int chunk = blockIdx.x & 7;
  int tid = threadIdx.x;
  int d0 = tid * 4;
  float* basef = batch_base(outb, b);
  __shared__ float qs[128];
  if (tid < 128) qs[tid] = basef[QC_OFF + chunk * 128 + tid];
  __syncthreads();
  float4 a = make_float4(0.f, 0.f, 0.f, 0.f);
#pragma unroll 4
  for (int dpl = 0; dpl < 128; dpl++) {
    int dp = chunk * 128 + dpl;
    float4 vv = *(const float4*)(v_w + (size_t)dp * Dd + d0);
    float qq = qs[dpl];
    a.x += qq * vv.x; a.y += qq * vv.y; a.z += qq * vv.z; a.w += qq * vv.w;
  }
  *(float4*)(basef + UP_OFF + chunk * Dd + d0) = a;
}

// ---------------------------------------------------------------------------
// K5: combine u partials + t[b] = qcls[b]·v_b. One block per batch.
// ---------------------------------------------------------------------------
__global__ __launch_bounds__(256) void combine_ut_kernel(
    const float* __restrict__ v_b, float* __restrict__ outb) {
  int b = blockIdx.x;
  int tid = threadIdx.x;
  float* basef = batch_base(outb, b);
  int d0 = tid * 4;
  float4 s = make_float4(0.f, 0.f, 0.f, 0.f);
#pragma unroll
  for (int c = 0; c < 8; c++) {
    float4 v = *(const float4*)(basef + UP_OFF + c * Dd + d0);
    s.x += v.x; s.y += v.y; s.z += v.z; s.w += v.w;
  }
  *(float4*)(basef + U_OFF + d0) = s;

  float a = 0.f;
  for (int i = tid; i < Dd; i += 256) a += basef[QC_OFF + i] * v_b[i];
  __shared__ float sh[256];
  sh[tid] = a;
  __syncthreads();
  for (int st = 128; st > 0; st >>= 1) {
    if (tid < st) sh[tid] += sh[tid + st];
    __syncthreads();
  }
  if (tid == 0) basef[T_OFF] = sh[0];
}

// ---------------------------------------------------------------------------
// K6: p[b,n] = patch[b,n]·u[b]. One wave per (b,n); float4; shuffle reduce.
// ---------------------------------------------------------------------------
__global__ __launch_bounds__(256) void ptok_kernel(
    const float* __restrict__ tok2d, float* __restrict__ outb) {
  int wave = threadIdx.x >> 6;
  int lane = threadIdx.x & 63;
  int gid = blockIdx.x * 4 + wave;
  int b = gid / Nn, n = gid % Nn;
  float* basef = batch_base(outb, b);
  const float* row = tok2d + (size_t)b * TOKSTRIDE + (size_t)(1 + n) * Dd;
  float a = 0.f;
#pragma unroll
  for (int i = 0; i < 4; i++) {
    float4 rv = *(const float4*)(row + lane * 4 + 256 * i);
    float4 uv = *(const float4*)(basef + U_OFF + lane * 4 + 256 * i);
    a += rv.x * uv.x + rv.y * uv.y + rv.z * uv.z + rv.w * uv.w;
  }
#pragma unroll
  for (int s = 32; s > 0; s >>= 1) a += __shfl_down(a, s, 64);
  if (lane == 0) basef[P_OFF + n] = a;
}

// ---------------------------------------------------------------------------
// K7: scores + top-128 (exact top_k ties) + per-row plan write, fused.
//     Plan phase striped over 4 waves.
// ---------------------------------------------------------------------------
__global__ __launch_bounds__(256) void scores_plan_kernel(float* __restrict__ outb) {
  int b = blockIdx.x;
  int tid = threadIdx.x;
  int wave = tid >> 6, lane = tid & 63;
  float* basef = batch_base(outb, b);
  int* base = (int*)basef;
  __shared__ int s_mem[Nn], s_off[Nn], s_ord[Kk], s_cnt[Kk], s_out[Mm];
  __shared__ float ss[Kk];
  __shared__ int sel[Kk];
  for (int i = tid; i < Nn; i += 256) {
    s_mem[i] = base[MEMB_OFF + i];
    s_off[i] = base[OFFS_OFF + i];
  }
  s_ord[tid] = base[ORD_OFF + tid];
  s_cnt[tid] = base[CNT_OFF + tid];
  float tt = basef[T_OFF];
  __syncthreads();

  // scores
  int idx = s_ord[tid];
  int c = s_cnt[tid];
  float s;
  if (c > 0) {
    int off = s_off[idx];
    float sum = 0.f;
    for (int j = 0; j < c; j++) sum += basef[P_OFF + s_mem[off + j]];
    s = (sum / (float)c + tt) * (1.0f / 32.0f);
  } else {
    s = -INFINITY;
  }
  ss[tid] = s;
  __syncthreads();

  // top-128 (value desc, index asc), ascending-index output
  float vk = ss[tid];
  int rank = 0;
  for (int m = 0; m < Kk; m++) {
    float vm = ss[m];
    rank += (vm > vk) || (vm == vk && m < tid);
  }
  sel[tid] = (rank < Mm) ? 1 : 0;
  __syncthreads();
  if (sel[tid]) {
    int pos = 0;
    for (int m = 0; m < tid; m++) pos += sel[m];
    s_out[pos] = tid;
  }
  __syncthreads();

  // plan: write [count, member ids...] into each of this batch's 128 rows
  for (int kp = wave; kp < Mm; kp += 4) {
    int k = s_out[kp];
    int kidx = s_ord[k];
    int kc = s_cnt[k];
    int koff = s_off[kidx];
    int* row = base + kp * Dd;
    if (lane == 0) row[0] = kc;
    for (int j = lane; j < kc; j += 64) row[1 + j] = s_mem[koff + j];
  }
}

// ---------------------------------------------------------------------------
// K8: output. One block per output row; reads its OWN row's plan into LDS,
//     then overwrites the row with the cluster mean. float4 over d.
// ---------------------------------------------------------------------------
__global__ __launch_bounds__(256) void output_kernel(
    const float* __restrict__ tok2d, float* __restrict__ outb) {
  int blk = blockIdx.x;  // b*Mm + kp
  int b = blk / Mm;
  int tid = threadIdx.x;
  float* rowf = outb + (size_t)blk * Dd;
  int* rowi = (int*)rowf;
  __shared__ int s_c;
  __shared__ int s_m[Nn];
  if (tid == 0) s_c = rowi[0];
  __syncthreads();
  int c = s_c;
  for (int j = tid; j < c; j += 256) s_m[j] = rowi[1 + j];
  __syncthreads();
  const float* patch = tok2d + (size_t)b * TOKSTRIDE + Dd;
  int d0 = tid * 4;
  float4 acc = make_float4(0.f, 0.f, 0.f, 0.f);
  for (int j = 0; j < c; j++) {
    float4 rv = *(const float4*)(patch + (size_t)s_m[j] * Dd + d0);
    acc.x += rv.x; acc.y += rv.y; acc.z += rv.z; acc.w += rv.w;
  }
  float inv = 1.0f / (float)max(c, 1);
  *(float4*)(rowf + d0) =
      make_float4(acc.x * inv, acc.y * inv, acc.z * inv, acc.w * inv);
}

// ---------------------------------------------------------------------------
extern "C" void kernel_launch(void* const* d_in, const int* in_sizes, int n_in,
                              void* d_out, int out_size, void* d_ws,
                              size_t ws_size, hipStream_t stream) {
  const float* tok2d = (const float*)d_in[0];
  const float* dw_w = (const float*)d_in[1];
  const float* pw_w = (const float*)d_in[2];
  const float* pw_b = (const float*)d_in[3];
  const float* q_w = (const float*)d_in[4];
  const float* q_b = (const float*)d_in[5];
  const float* v_w = (const float*)d_in[6];
  const float* v_b = (const float*)d_in[7];
  float* out = (float*)d_out;
  (void)d_ws; (void)ws_size;  // d_ws intentionally unused

  affinity_part_kernel<<<dim3(Bb * Nn), dim3(256), 0, stream>>>(
      tok2d, dw_w, pw_w, out);
  affinity_fin_kernel<<<dim3(Bb * Nn / 256), dim3(256), 0, stream>>>(pw_b, out);
  cluster_topk_kernel<<<dim3(Bb), dim3(Nn), 0, stream>>>(out);
  qcls_kernel<<<dim3(Dd), dim3(256), 0, stream>>>(tok2d, q_w, q_b, out);
  u_part_kernel<<<dim3(Bb * 8), dim3(256), 0, stream>>>(v_w, out);
  combine_ut_kernel<<<dim3(Bb), dim3(256), 0, stream>>>(v_b, out);
  ptok_kernel<<<dim3(Bb * Nn / 4), dim3(256), 0, stream>>>(tok2d, out);
  scores_plan_kernel<<<dim3(Bb), dim3(256), 0, stream>>>(out);
  output_kernel<<<dim3(Bb * Mm), dim3(256), 0, stream>>>(tok2d, out);
}